// Round 9
// baseline (190.976 us; speedup 1.0000x reference)
//
#include <hip/hip_runtime.h>
#include <hip/hip_bf16.h>
#include <cfloat>
#include <cmath>

#define B_ 4
#define S_ 512
#define D_ 768
#define H_ 12
#define NE_ 42
#define M_ 8
#define OFFSET_ 1
#define NE2_ (NE_*NE_)
#define OUTC_ (3*D_)   // 2304
#define HS_ (H_*S_)    // 6144
#define MPAD_ 1792     // 14 * 128, padded M for the MFMA GEMM

typedef __attribute__((ext_vector_type(8))) short short8;
typedef __attribute__((ext_vector_type(4))) float f32x4;

#define GLOAD_LDS16(g, l) __builtin_amdgcn_global_load_lds( \
    (const __attribute__((address_space(1))) unsigned int*)(g), \
    (__attribute__((address_space(3))) unsigned int*)(l), 16, 0, 0)

// ---------------------------------------------------------------------------
// K0: seqT[b][d][s] = bf16(seq[b][s][d])  — 64x64 LDS tile transpose
// grid = (D/64=12, S/64=8, B)
// ---------------------------------------------------------------------------
__global__ void k_prep(const float* __restrict__ seq, __hip_bfloat16* __restrict__ seqT) {
    const int b  = blockIdx.z;
    const int s0 = blockIdx.y * 64;
    const int d0 = blockIdx.x * 64;
    const int t  = threadIdx.x;

    __shared__ float tile[64][65];
#pragma unroll
    for (int i = 0; i < 16; ++i) {
        const int r = (t >> 6) * 16 + i;   // s within tile
        const int c = t & 63;              // d within tile
        tile[r][c] = seq[((size_t)b * S_ + s0 + r) * D_ + d0 + c];
    }
    __syncthreads();
#pragma unroll
    for (int i = 0; i < 16; ++i) {
        const int r = (t >> 6) * 16 + i;   // d within tile
        const int c = t & 63;              // s within tile
        seqT[((size_t)b * D_ + d0 + r) * S_ + s0 + c] = __float2bfloat16(tile[c][r]);
    }
}

// ---------------------------------------------------------------------------
// K1a: ent_att[b,e,h,s] = masked mean over mentions of attention[b,h,pos,s]
// grid = B*NE*H blocks, 256 threads (each thread: s and s+256)
// Blocks 0..6 additionally zero Gsum (needed by k_ht_raw's atomics).
// ---------------------------------------------------------------------------
__global__ void k_ent_att(const float* __restrict__ att, const int* __restrict__ mpos,
                          const int* __restrict__ mmask, float* __restrict__ ent_att,
                          float* __restrict__ Gsum) {
    // zero Gsum: 7 blocks x 1024 floats covers B*NE2 = 7056
    if (blockIdx.x < 7) {
#pragma unroll
        for (int k = 0; k < 4; ++k) {
            const int idx = blockIdx.x * 1024 + k * 256 + threadIdx.x;
            if (idx < B_ * NE2_) Gsum[idx] = 0.0f;
        }
    }

    const int beh = blockIdx.x;
    const int h   = beh % H_;
    const int be  = beh / H_;
    const int b   = be / NE_;

    __shared__ int sp[M_];
    __shared__ int sv[M_];
    if (threadIdx.x < M_) {
        int p  = mpos[be * M_ + threadIdx.x] + OFFSET_;
        int v  = (mmask[be * M_ + threadIdx.x] > 0) && (p < S_);
        int pc = p < 0 ? 0 : (p > S_ - 1 ? S_ - 1 : p);
        sp[threadIdx.x] = pc;
        sv[threadIdx.x] = v;
    }
    __syncthreads();

    int cnt = 0;
#pragma unroll
    for (int m = 0; m < M_; ++m) cnt += sv[m];
    const float inv_cnt = 1.0f / (float)(cnt > 0 ? cnt : 1);

    const float* arow = att + ((size_t)b * H_ + h) * S_ * S_;
    const int s0 = threadIdx.x;
    const int s1 = threadIdx.x + 256;
    float a0 = 0.0f, a1 = 0.0f;
#pragma unroll
    for (int m = 0; m < M_; ++m) {
        if (sv[m]) {
            a0 += arow[(size_t)sp[m] * S_ + s0];
            a1 += arow[(size_t)sp[m] * S_ + s1];
        }
    }
    float* dst = ent_att + ((size_t)be * H_ + h) * S_;
    dst[s0] = a0 * inv_cnt;
    dst[s1] = a1 * inv_cnt;
}

// ---------------------------------------------------------------------------
// K1b: ent_emb[b,e,d] = logsumexp over valid mentions of seq rows
// grid = B*NE blocks, 256 threads
// ---------------------------------------------------------------------------
__global__ void k_ent_emb(const float* __restrict__ seq, const int* __restrict__ mpos,
                          const int* __restrict__ mmask, float* __restrict__ ent_emb) {
    const int be = blockIdx.x;
    const int b  = be / NE_;

    __shared__ int sp[M_];
    __shared__ int sv[M_];
    if (threadIdx.x < M_) {
        int p  = mpos[be * M_ + threadIdx.x] + OFFSET_;
        int v  = (mmask[be * M_ + threadIdx.x] > 0) && (p < S_);
        int pc = p < 0 ? 0 : (p > S_ - 1 ? S_ - 1 : p);
        sp[threadIdx.x] = pc;
        sv[threadIdx.x] = v;
    }
    __syncthreads();

    int cnt = 0;
#pragma unroll
    for (int m = 0; m < M_; ++m) cnt += sv[m];
    const bool has = cnt > 0;

    for (int d = threadIdx.x; d < D_; d += blockDim.x) {
        float vals[M_];
        float mx = -FLT_MAX;
#pragma unroll
        for (int m = 0; m < M_; ++m) {
            float v = sv[m] ? seq[((size_t)b * S_ + sp[m]) * D_ + d] : -FLT_MAX;
            vals[m] = v;
            mx = fmaxf(mx, v);
        }
        float o = 0.0f;
        if (has) {
            float ss = 0.0f;
#pragma unroll
            for (int m = 0; m < M_; ++m)
                if (sv[m]) ss += expf(vals[m] - mx);
            o = mx + logf(ss);
        }
        ent_emb[(size_t)be * D_ + d] = o;
    }
}

// ---------------------------------------------------------------------------
// K2: k_ht_raw — raw[b,ij,s] = sum_h Ai[h,s]*Aj[h,s] (bf16, unnormalized),
// plus Gsum[b,ij] = sum_s raw (fp32 atomics). Normalization is deferred to
// the GEMM epilogue (row-wise, commutes with the GEMM).
// Grid = (S/8 = 64 s-chunks, B). Each block stages ALL 42 entities x 12 h x 8 s
// into LDS once (global reads = 4 MB total, the minimum), then 196 threads
// each own a 3x3 (i,j) tile for all 8 s.
// LDS per-entity stride padded to 100 floats to break bank alignment.
// ---------------------------------------------------------------------------
__global__ void k_ht_raw(const float* __restrict__ ent_att,
                         __hip_bfloat16* __restrict__ raw,
                         float* __restrict__ Gsum) {
    const int sc0 = blockIdx.x * 8;     // s-chunk start
    const int b   = blockIdx.y;
    const int t   = threadIdx.x;

    __shared__ float lds[NE_ * 100];    // [e][h*8 + s], stride 100 (pad 4)

    // stage: 42*12*8 floats = 1008 float4 loads
#pragma unroll
    for (int k = 0; k < 4; ++k) {
        const int q = t + k * 256;
        if (q < 1008) {
            const int e   = q / 24;
            const int rem = q - e * 24;
            const int h   = rem >> 1;
            const int s4  = (rem & 1) * 4;
            const float4 v = *reinterpret_cast<const float4*>(
                &ent_att[(((size_t)b * NE_ + e) * H_ + h) * S_ + sc0 + s4]);
            *reinterpret_cast<float4*>(&lds[e * 100 + h * 8 + s4]) = v;
        }
    }
    __syncthreads();

    if (t >= 196) return;
    const int ti = t / 14;
    const int tj = t - ti * 14;
    const int i0 = ti * 3, j0 = tj * 3;

    float acc[3][3][8];
#pragma unroll
    for (int di = 0; di < 3; ++di)
#pragma unroll
        for (int dj = 0; dj < 3; ++dj)
#pragma unroll
            for (int v = 0; v < 8; ++v) acc[di][dj][v] = 0.0f;

#pragma unroll
    for (int s4 = 0; s4 < 2; ++s4) {
#pragma unroll
        for (int h = 0; h < H_; ++h) {
            float4 ai[3], aj[3];
#pragma unroll
            for (int di = 0; di < 3; ++di)
                ai[di] = *reinterpret_cast<const float4*>(&lds[(i0 + di) * 100 + h * 8 + s4 * 4]);
#pragma unroll
            for (int dj = 0; dj < 3; ++dj)
                aj[dj] = *reinterpret_cast<const float4*>(&lds[(j0 + dj) * 100 + h * 8 + s4 * 4]);
#pragma unroll
            for (int di = 0; di < 3; ++di)
#pragma unroll
                for (int dj = 0; dj < 3; ++dj) {
#pragma unroll
                    for (int v = 0; v < 4; ++v)
                        acc[di][dj][s4 * 4 + v] = fmaf(ai[di][v], aj[dj][v], acc[di][dj][s4 * 4 + v]);
                }
        }
    }

    // write raw (16B per pair) + atomic partial sum
#pragma unroll
    for (int di = 0; di < 3; ++di) {
#pragma unroll
        for (int dj = 0; dj < 3; ++dj) {
            const int pair = (i0 + di) * NE_ + (j0 + dj);
            __hip_bfloat16 tmp[8];
            float g = 0.0f;
#pragma unroll
            for (int v = 0; v < 8; ++v) {
                g += acc[di][dj][v];
                tmp[v] = __float2bfloat16(acc[di][dj][v]);
            }
            *reinterpret_cast<short8*>(&raw[((size_t)b * MPAD_ + pair) * S_ + sc0]) =
                *reinterpret_cast<short8*>(tmp);
            atomicAdd(&Gsum[b * NE2_ + pair], g);
        }
    }
}

// ---------------------------------------------------------------------------
// K3: rs = (raw @ seq) * rowscale via bf16 MFMA (m97 structure).
// A = raw (MPAD x 512) bf16, B^T = seqT (768 x 512) bf16, C fp32 -> out[...,1536:].
// Epilogue applies 1/(G + H*1e-5) per output row (deferred ht normalization).
// 128x128 tile, BK=32, 256 threads = 4 waves (2x2), each wave 64x64.
// grid = (N/128=6, MPAD/128=14, B)
// ---------------------------------------------------------------------------
__global__ void __launch_bounds__(256)
k_gemm(const __hip_bfloat16* __restrict__ htb, const __hip_bfloat16* __restrict__ seqT,
       const float* __restrict__ Gsum, float* __restrict__ out) {
    const int b     = blockIdx.z;
    const int tileN = blockIdx.x * 128;
    const int tileM = blockIdx.y * 128;
    const int tid   = threadIdx.x;
    const int w     = tid >> 6;
    const int lane  = tid & 63;
    const int wr    = w >> 1;          // wave row (0..1)
    const int wc    = w & 1;           // wave col (0..1)

    __shared__ unsigned short As[128 * 32];   // [row][k] 8KB
    __shared__ unsigned short Bs[128 * 32];   // [col][k] 8KB

    const __hip_bfloat16* A = htb  + (size_t)b * MPAD_ * S_;
    const __hip_bfloat16* Bt = seqT + (size_t)b * D_ * S_;

    // staging geometry: 8 chunks per tile, chunk = 16 rows x 32 cols = 1KB
    const int crow = lane >> 2;          // row within chunk (0..15)
    const int ccol = (lane & 3) * 8;     // k within chunk (0,8,16,24)

    // fragment geometry
    const int lr = lane & 15;
    const int lk = (lane >> 4) * 8;

    f32x4 acc[4][4];
#pragma unroll
    for (int mf = 0; mf < 4; ++mf)
#pragma unroll
        for (int nf = 0; nf < 4; ++nf) acc[mf][nf] = (f32x4){0.f, 0.f, 0.f, 0.f};

    for (int k0 = 0; k0 < S_; k0 += 32) {
#pragma unroll
        for (int q = 0; q < 2; ++q) {
            const int c = w * 2 + q;
            const __hip_bfloat16* ga = A + (size_t)(tileM + c * 16 + crow) * S_ + k0 + ccol;
            GLOAD_LDS16(ga, As + c * 512);
            const __hip_bfloat16* gb = Bt + (size_t)(tileN + c * 16 + crow) * S_ + k0 + ccol;
            GLOAD_LDS16(gb, Bs + c * 512);
        }
        __syncthreads();

        short8 af[4], bf[4];
#pragma unroll
        for (int mf = 0; mf < 4; ++mf)
            af[mf] = *(const short8*)&As[(wr * 64 + mf * 16 + lr) * 32 + lk];
#pragma unroll
        for (int nf = 0; nf < 4; ++nf)
            bf[nf] = *(const short8*)&Bs[(wc * 64 + nf * 16 + lr) * 32 + lk];
#pragma unroll
        for (int mf = 0; mf < 4; ++mf)
#pragma unroll
            for (int nf = 0; nf < 4; ++nf)
                acc[mf][nf] = __builtin_amdgcn_mfma_f32_16x16x32_bf16(af[mf], bf[nf], acc[mf][nf], 0, 0, 0);
        __syncthreads();
    }

    // epilogue: C/D layout col=lane&15, row=(lane>>4)*4+j; apply row scale
#pragma unroll
    for (int mf = 0; mf < 4; ++mf) {
        const int row0 = tileM + wr * 64 + mf * 16 + (lane >> 4) * 4;
#pragma unroll
        for (int nf = 0; nf < 4; ++nf) {
            const int col = tileN + wc * 64 + nf * 16 + (lane & 15);
#pragma unroll
            for (int j = 0; j < 4; ++j) {
                const int r = row0 + j;
                if (r < NE2_) {
                    const float g  = Gsum[b * NE2_ + r];
                    const float sc = 1.0f / (g + (float)H_ * 1e-5f);
                    out[((size_t)(b * NE2_ + r)) * OUTC_ + 2 * D_ + col] = acc[mf][nf][j] * sc;
                }
            }
        }
    }
}

// ---------------------------------------------------------------------------
// K4: hs/ts broadcast writes
// ---------------------------------------------------------------------------
__global__ void k_hsts(const float* __restrict__ ent_emb, float* __restrict__ out) {
    const int bij = blockIdx.x;
    const int b   = bij / NE2_;
    const int ij  = bij - b * NE2_;
    const int i   = ij / NE_;
    const int j   = ij - i * NE_;

    const float4* ei = reinterpret_cast<const float4*>(ent_emb + ((size_t)b * NE_ + i) * D_);
    const float4* ej = reinterpret_cast<const float4*>(ent_emb + ((size_t)b * NE_ + j) * D_);
    float4* o = reinterpret_cast<float4*>(out + (size_t)bij * OUTC_);

    for (int t = threadIdx.x; t < D_ / 4; t += blockDim.x) o[t] = ei[t];
    for (int t = threadIdx.x; t < D_ / 4; t += blockDim.x) o[D_ / 4 + t] = ej[t];
}

// ---------------------------------------------------------------------------
extern "C" void kernel_launch(void* const* d_in, const int* in_sizes, int n_in,
                              void* d_out, int out_size, void* d_ws, size_t ws_size,
                              hipStream_t stream) {
    const float* seq   = (const float*)d_in[0];
    const float* att   = (const float*)d_in[1];
    const int*   mpos  = (const int*)d_in[2];
    const int*   mmask = (const int*)d_in[3];
    float* out = (float*)d_out;

    // workspace layout
    float* ent_emb = (float*)d_ws;                               // B*NE*D   fp32
    float* ent_att = ent_emb + (size_t)B_ * NE_ * D_;            // B*NE*H*S fp32
    float* Gsum    = ent_att + (size_t)B_ * NE_ * HS_;           // B*NE2    fp32
    __hip_bfloat16* htraw = (__hip_bfloat16*)(Gsum + (size_t)B_ * NE2_); // B*MPAD*S bf16
    __hip_bfloat16* seqT  = htraw + (size_t)B_ * MPAD_ * S_;     // B*D*S bf16

    k_prep<<<dim3(D_ / 64, S_ / 64, B_), 256, 0, stream>>>(seq, seqT);
    k_ent_att<<<B_ * NE_ * H_, 256, 0, stream>>>(att, mpos, mmask, ent_att, Gsum);
    k_ent_emb<<<B_ * NE_, 256, 0, stream>>>(seq, mpos, mmask, ent_emb);
    k_ht_raw<<<dim3(S_ / 8, B_), 256, 0, stream>>>(ent_att, htraw, Gsum);
    k_gemm<<<dim3(D_ / 128, MPAD_ / 128, B_), 256, 0, stream>>>(htraw, seqT, Gsum, out);
    k_hsts<<<B_ * NE2_, 256, 0, stream>>>(ent_emb, out);
}

// Round 11
// 157.004 us; speedup vs baseline: 1.2164x; 1.2164x over previous
//
#include <hip/hip_runtime.h>
#include <hip/hip_bf16.h>
#include <cfloat>
#include <cmath>

#define B_ 4
#define S_ 512
#define D_ 768
#define H_ 12
#define NE_ 42
#define M_ 8
#define OFFSET_ 1
#define NE2_ (NE_*NE_)
#define OUTC_ (3*D_)   // 2304
#define HS_ (H_*S_)    // 6144
#define MPAD_ 1792     // 14 * 128, padded M for the MFMA GEMM

typedef __attribute__((ext_vector_type(8))) short short8;
typedef __attribute__((ext_vector_type(4))) float f32x4;

#define GLOAD_LDS16(g, l) __builtin_amdgcn_global_load_lds( \
    (const __attribute__((address_space(1))) unsigned int*)(g), \
    (__attribute__((address_space(3))) unsigned int*)(l), 16, 0, 0)

// ---------------------------------------------------------------------------
// K0: seqT[b][d][s] = bf16(seq[b][s][d])  — 64x64 LDS tile transpose
// grid = (D/64=12, S/64=8, B)
// ---------------------------------------------------------------------------
__global__ void k_prep(const float* __restrict__ seq, __hip_bfloat16* __restrict__ seqT) {
    const int b  = blockIdx.z;
    const int s0 = blockIdx.y * 64;
    const int d0 = blockIdx.x * 64;
    const int t  = threadIdx.x;

    __shared__ float tile[64][65];
#pragma unroll
    for (int i = 0; i < 16; ++i) {
        const int r = (t >> 6) * 16 + i;   // s within tile
        const int c = t & 63;              // d within tile
        tile[r][c] = seq[((size_t)b * S_ + s0 + r) * D_ + d0 + c];
    }
    __syncthreads();
#pragma unroll
    for (int i = 0; i < 16; ++i) {
        const int r = (t >> 6) * 16 + i;   // d within tile
        const int c = t & 63;              // s within tile
        seqT[((size_t)b * D_ + d0 + r) * S_ + s0 + c] = __float2bfloat16(tile[c][r]);
    }
}

// ---------------------------------------------------------------------------
// K1a: ent_att[b,e,h,s] = masked mean over mentions of attention[b,h,pos,s]
// grid = B*NE*H blocks, 256 threads (each thread: s and s+256)
// ---------------------------------------------------------------------------
__global__ void k_ent_att(const float* __restrict__ att, const int* __restrict__ mpos,
                          const int* __restrict__ mmask, float* __restrict__ ent_att) {
    const int beh = blockIdx.x;
    const int h   = beh % H_;
    const int be  = beh / H_;
    const int b   = be / NE_;

    __shared__ int sp[M_];
    __shared__ int sv[M_];
    if (threadIdx.x < M_) {
        int p  = mpos[be * M_ + threadIdx.x] + OFFSET_;
        int v  = (mmask[be * M_ + threadIdx.x] > 0) && (p < S_);
        int pc = p < 0 ? 0 : (p > S_ - 1 ? S_ - 1 : p);
        sp[threadIdx.x] = pc;
        sv[threadIdx.x] = v;
    }
    __syncthreads();

    int cnt = 0;
#pragma unroll
    for (int m = 0; m < M_; ++m) cnt += sv[m];
    const float inv_cnt = 1.0f / (float)(cnt > 0 ? cnt : 1);

    const float* arow = att + ((size_t)b * H_ + h) * S_ * S_;
    const int s0 = threadIdx.x;
    const int s1 = threadIdx.x + 256;
    float a0 = 0.0f, a1 = 0.0f;
#pragma unroll
    for (int m = 0; m < M_; ++m) {
        if (sv[m]) {
            a0 += arow[(size_t)sp[m] * S_ + s0];
            a1 += arow[(size_t)sp[m] * S_ + s1];
        }
    }
    float* dst = ent_att + ((size_t)be * H_ + h) * S_;
    dst[s0] = a0 * inv_cnt;
    dst[s1] = a1 * inv_cnt;
}

// ---------------------------------------------------------------------------
// K1b: ent_emb[b,e,d] = logsumexp over valid mentions of seq rows
// grid = B*NE blocks, 256 threads
// ---------------------------------------------------------------------------
__global__ void k_ent_emb(const float* __restrict__ seq, const int* __restrict__ mpos,
                          const int* __restrict__ mmask, float* __restrict__ ent_emb) {
    const int be = blockIdx.x;
    const int b  = be / NE_;

    __shared__ int sp[M_];
    __shared__ int sv[M_];
    if (threadIdx.x < M_) {
        int p  = mpos[be * M_ + threadIdx.x] + OFFSET_;
        int v  = (mmask[be * M_ + threadIdx.x] > 0) && (p < S_);
        int pc = p < 0 ? 0 : (p > S_ - 1 ? S_ - 1 : p);
        sp[threadIdx.x] = pc;
        sv[threadIdx.x] = v;
    }
    __syncthreads();

    int cnt = 0;
#pragma unroll
    for (int m = 0; m < M_; ++m) cnt += sv[m];
    const bool has = cnt > 0;

    for (int d = threadIdx.x; d < D_; d += blockDim.x) {
        float vals[M_];
        float mx = -FLT_MAX;
#pragma unroll
        for (int m = 0; m < M_; ++m) {
            float v = sv[m] ? seq[((size_t)b * S_ + sp[m]) * D_ + d] : -FLT_MAX;
            vals[m] = v;
            mx = fmaxf(mx, v);
        }
        float o = 0.0f;
        if (has) {
            float ss = 0.0f;
#pragma unroll
            for (int m = 0; m < M_; ++m)
                if (sv[m]) ss += expf(vals[m] - mx);
            o = mx + logf(ss);
        }
        ent_emb[(size_t)be * D_ + d] = o;
    }
}

// ---------------------------------------------------------------------------
// K2: ht[b,ij,s] (bf16, M padded to 1792) = normalized mean_h product.
// Measured-good per-pair-block structure (coalesced L2 reads, 7168 blocks),
// float2 loads + bf16x2 stores.
// grid = dim3(MPAD_, B_), 256 threads (thread t owns s=2t, 2t+1)
// ---------------------------------------------------------------------------
__global__ void k_ht(const float* __restrict__ ent_att, __hip_bfloat16* __restrict__ htb) {
    const int ij = blockIdx.x;
    const int b  = blockIdx.y;
    const int t  = threadIdx.x;
    __hip_bfloat16* dst = htb + ((size_t)b * MPAD_ + ij) * S_;

    if (ij >= NE2_) {           // zero the M padding rows
        __hip_bfloat162 z;
        z.x = __float2bfloat16(0.0f);
        z.y = __float2bfloat16(0.0f);
        *reinterpret_cast<__hip_bfloat162*>(&dst[2 * t]) = z;
        return;
    }
    const int i = ij / NE_;
    const int j = ij - i * NE_;

    const float* Ai = ent_att + ((size_t)b * NE_ + i) * HS_;
    const float* Aj = ent_att + ((size_t)b * NE_ + j) * HS_;

    float v0 = 0.0f, v1 = 0.0f;
#pragma unroll
    for (int h = 0; h < H_; ++h) {
        const float2 a = *reinterpret_cast<const float2*>(&Ai[h * S_ + 2 * t]);
        const float2 c = *reinterpret_cast<const float2*>(&Aj[h * S_ + 2 * t]);
        v0 = fmaf(a.x, c.x, v0);
        v1 = fmaf(a.y, c.y, v1);
    }
    v0 *= (1.0f / H_);
    v1 *= (1.0f / H_);

    float local = v0 + v1;
#pragma unroll
    for (int off = 32; off > 0; off >>= 1) local += __shfl_xor(local, off, 64);
    __shared__ float wsum[4];
    if ((t & 63) == 0) wsum[t >> 6] = local;
    __syncthreads();
    const float inv = 1.0f / (wsum[0] + wsum[1] + wsum[2] + wsum[3] + 1e-5f);

    __hip_bfloat162 r;
    r.x = __float2bfloat16(v0 * inv);
    r.y = __float2bfloat16(v1 * inv);
    *reinterpret_cast<__hip_bfloat162*>(&dst[2 * t]) = r;
}

// ---------------------------------------------------------------------------
// K3: rs = ht @ seq via bf16 MFMA.
// A = htb (MPAD x 512) bf16, B^T = seqT (768 x 512) bf16, C fp32 -> out[...,1536:].
// 128x64 tile (BN=64 -> 672 blocks = 2.6/CU), BK=32, double-buffered LDS with
// prefetch-before-compute: issue next tile's global_load_lds, compute current,
// then barrier (its vmcnt drain overlaps with the MFMA phase).
// 256 threads = 4 waves (2x2), each wave 64x32.
// grid = (D/64=12, MPAD/128=14, B)
// ---------------------------------------------------------------------------
__global__ void __launch_bounds__(256)
k_gemm(const __hip_bfloat16* __restrict__ htb, const __hip_bfloat16* __restrict__ seqT,
       float* __restrict__ out) {
    const int b     = blockIdx.z;
    const int tileN = blockIdx.x * 64;
    const int tileM = blockIdx.y * 128;
    const int tid   = threadIdx.x;
    const int w     = tid >> 6;
    const int lane  = tid & 63;
    const int wr    = w >> 1;          // wave row (0..1) -> 64 rows each
    const int wc    = w & 1;           // wave col (0..1) -> 32 cols each

    __shared__ unsigned short As[2][128 * 32];   // [buf][row][k] 8KB each
    __shared__ unsigned short Bs[2][64 * 32];    // [buf][col][k] 4KB each

    const __hip_bfloat16* A  = htb  + (size_t)b * MPAD_ * S_;
    const __hip_bfloat16* Bt = seqT + (size_t)b * D_ * S_;

    // staging geometry: chunk = 16 rows x 32 cols = 1KB per wave-load
    const int crow = lane >> 2;          // row within chunk (0..15)
    const int ccol = (lane & 3) * 8;     // k within chunk (0,8,16,24)

    // fragment geometry
    const int lr = lane & 15;
    const int lk = (lane >> 4) * 8;

    f32x4 acc[4][2];
#pragma unroll
    for (int mf = 0; mf < 4; ++mf)
#pragma unroll
        for (int nf = 0; nf < 2; ++nf) acc[mf][nf] = (f32x4){0.f, 0.f, 0.f, 0.f};

    // prologue: stage k-tile 0 into buffer 0
    {
#pragma unroll
        for (int q = 0; q < 2; ++q) {
            const int c = w * 2 + q;     // A chunks 0..7
            GLOAD_LDS16(A + (size_t)(tileM + c * 16 + crow) * S_ + ccol, &As[0][c * 512]);
        }
        GLOAD_LDS16(Bt + (size_t)(tileN + w * 16 + crow) * S_ + ccol, &Bs[0][w * 512]);
    }
    __syncthreads();

    for (int it = 0; it < 16; ++it) {
        const int cur = it & 1;
        // prefetch next k-tile into the other buffer (overlaps with MFMA below)
        if (it < 15) {
            const int k0 = (it + 1) * 32;
#pragma unroll
            for (int q = 0; q < 2; ++q) {
                const int c = w * 2 + q;
                GLOAD_LDS16(A + (size_t)(tileM + c * 16 + crow) * S_ + k0 + ccol,
                            &As[cur ^ 1][c * 512]);
            }
            GLOAD_LDS16(Bt + (size_t)(tileN + w * 16 + crow) * S_ + k0 + ccol,
                        &Bs[cur ^ 1][w * 512]);
        }

        short8 af[4], bfr[2];
#pragma unroll
        for (int mf = 0; mf < 4; ++mf)
            af[mf] = *(const short8*)&As[cur][(wr * 64 + mf * 16 + lr) * 32 + lk];
#pragma unroll
        for (int nf = 0; nf < 2; ++nf)
            bfr[nf] = *(const short8*)&Bs[cur][(wc * 32 + nf * 16 + lr) * 32 + lk];
#pragma unroll
        for (int mf = 0; mf < 4; ++mf)
#pragma unroll
            for (int nf = 0; nf < 2; ++nf)
                acc[mf][nf] = __builtin_amdgcn_mfma_f32_16x16x32_bf16(af[mf], bfr[nf], acc[mf][nf], 0, 0, 0);

        __syncthreads();   // drains this iteration's prefetch (vmcnt) + readers
    }

    // epilogue: C/D layout col=lane&15, row=(lane>>4)*4+j
#pragma unroll
    for (int mf = 0; mf < 4; ++mf) {
        const int row0 = tileM + wr * 64 + mf * 16 + (lane >> 4) * 4;
#pragma unroll
        for (int nf = 0; nf < 2; ++nf) {
            const int col = tileN + wc * 32 + nf * 16 + (lane & 15);
#pragma unroll
            for (int j = 0; j < 4; ++j) {
                const int r = row0 + j;
                if (r < NE2_)
                    out[((size_t)(b * NE2_ + r)) * OUTC_ + 2 * D_ + col] = acc[mf][nf][j];
            }
        }
    }
}

// ---------------------------------------------------------------------------
// K4: hs/ts broadcast writes
// ---------------------------------------------------------------------------
__global__ void k_hsts(const float* __restrict__ ent_emb, float* __restrict__ out) {
    const int bij = blockIdx.x;
    const int b   = bij / NE2_;
    const int ij  = bij - b * NE2_;
    const int i   = ij / NE_;
    const int j   = ij - i * NE_;

    const float4* ei = reinterpret_cast<const float4*>(ent_emb + ((size_t)b * NE_ + i) * D_);
    const float4* ej = reinterpret_cast<const float4*>(ent_emb + ((size_t)b * NE_ + j) * D_);
    float4* o = reinterpret_cast<float4*>(out + (size_t)bij * OUTC_);

    for (int t = threadIdx.x; t < D_ / 4; t += blockDim.x) o[t] = ei[t];
    for (int t = threadIdx.x; t < D_ / 4; t += blockDim.x) o[D_ / 4 + t] = ej[t];
}

// ---------------------------------------------------------------------------
extern "C" void kernel_launch(void* const* d_in, const int* in_sizes, int n_in,
                              void* d_out, int out_size, void* d_ws, size_t ws_size,
                              hipStream_t stream) {
    const float* seq   = (const float*)d_in[0];
    const float* att   = (const float*)d_in[1];
    const int*   mpos  = (const int*)d_in[2];
    const int*   mmask = (const int*)d_in[3];
    float* out = (float*)d_out;

    // workspace layout
    float* ent_emb = (float*)d_ws;                               // B*NE*D   fp32
    float* ent_att = ent_emb + (size_t)B_ * NE_ * D_;            // B*NE*H*S fp32
    __hip_bfloat16* htb  = (__hip_bfloat16*)(ent_att + (size_t)B_ * NE_ * HS_); // B*MPAD*S bf16
    __hip_bfloat16* seqT = htb + (size_t)B_ * MPAD_ * S_;        // B*D*S bf16

    k_prep<<<dim3(D_ / 64, S_ / 64, B_), 256, 0, stream>>>(seq, seqT);
    k_ent_att<<<B_ * NE_ * H_, 256, 0, stream>>>(att, mpos, mmask, ent_att);
    k_ent_emb<<<B_ * NE_, 256, 0, stream>>>(seq, mpos, mmask, ent_emb);
    k_ht<<<dim3(MPAD_, B_), 256, 0, stream>>>(ent_att, htb);
    k_gemm<<<dim3(D_ / 64, MPAD_ / 128, B_), 256, 0, stream>>>(htb, seqT, out);
    k_hsts<<<B_ * NE2_, 256, 0, stream>>>(ent_emb, out);
}

// Round 14
// 151.401 us; speedup vs baseline: 1.2614x; 1.0370x over previous
//
#include <hip/hip_runtime.h>
#include <hip/hip_bf16.h>
#include <cfloat>
#include <cmath>

#define B_ 4
#define S_ 512
#define D_ 768
#define H_ 12
#define NE_ 42
#define M_ 8
#define OFFSET_ 1
#define NE2_ (NE_*NE_)
#define OUTC_ (3*D_)   // 2304
#define HS_ (H_*S_)    // 6144
#define NU_ 903        // NE*(NE+1)/2 unique (i<=j) pairs
#define MU_ 1024       // padded unique-pair rows for the MFMA GEMM (8 * 128)

typedef __attribute__((ext_vector_type(8))) short short8;
typedef __attribute__((ext_vector_type(4))) float f32x4;

#define GLOAD_LDS16(g, l) __builtin_amdgcn_global_load_lds( \
    (const __attribute__((address_space(1))) unsigned int*)(g), \
    (__attribute__((address_space(3))) unsigned int*)(l), 16, 0, 0)

// triangle-pair index inversion: r = base(i) + (j - i), base(i) = i*(85-i)/2
__device__ __forceinline__ int tri_base(int i) { return (i * (2 * NE_ + 1 - i)) >> 1; }
__device__ __forceinline__ void tri_inv(int r, int& i, int& j) {
    i = (int)floorf(((float)(2 * NE_ + 1)
                     - sqrtf((float)((2 * NE_ + 1) * (2 * NE_ + 1)) - 8.0f * (float)r)) * 0.5f);
    if (i < 0) i = 0;
    while (tri_base(i + 1) <= r) ++i;
    while (tri_base(i) > r) --i;
    j = i + (r - tri_base(i));
}

// ---------------------------------------------------------------------------
// K0: seqT[b][d][s] = bf16(seq[b][s][d])  — 64x64 LDS tile transpose
// grid = (D/64=12, S/64=8, B)
// ---------------------------------------------------------------------------
__global__ void k_prep(const float* __restrict__ seq, __hip_bfloat16* __restrict__ seqT) {
    const int b  = blockIdx.z;
    const int s0 = blockIdx.y * 64;
    const int d0 = blockIdx.x * 64;
    const int t  = threadIdx.x;

    __shared__ float tile[64][65];
#pragma unroll
    for (int i = 0; i < 16; ++i) {
        const int r = (t >> 6) * 16 + i;   // s within tile
        const int c = t & 63;              // d within tile
        tile[r][c] = seq[((size_t)b * S_ + s0 + r) * D_ + d0 + c];
    }
    __syncthreads();
#pragma unroll
    for (int i = 0; i < 16; ++i) {
        const int r = (t >> 6) * 16 + i;   // d within tile
        const int c = t & 63;              // s within tile
        seqT[((size_t)b * D_ + d0 + r) * S_ + s0 + c] = __float2bfloat16(tile[c][r]);
    }
}

// ---------------------------------------------------------------------------
// K1a: ent_att[b,e,h,s] = masked mean over mentions of attention[b,h,pos,s]
// grid = B*NE*H blocks, 256 threads (each thread: s and s+256)
// ---------------------------------------------------------------------------
__global__ void k_ent_att(const float* __restrict__ att, const int* __restrict__ mpos,
                          const int* __restrict__ mmask, float* __restrict__ ent_att) {
    const int beh = blockIdx.x;
    const int h   = beh % H_;
    const int be  = beh / H_;
    const int b   = be / NE_;

    __shared__ int sp[M_];
    __shared__ int sv[M_];
    if (threadIdx.x < M_) {
        int p  = mpos[be * M_ + threadIdx.x] + OFFSET_;
        int v  = (mmask[be * M_ + threadIdx.x] > 0) && (p < S_);
        int pc = p < 0 ? 0 : (p > S_ - 1 ? S_ - 1 : p);
        sp[threadIdx.x] = pc;
        sv[threadIdx.x] = v;
    }
    __syncthreads();

    int cnt = 0;
#pragma unroll
    for (int m = 0; m < M_; ++m) cnt += sv[m];
    const float inv_cnt = 1.0f / (float)(cnt > 0 ? cnt : 1);

    const float* arow = att + ((size_t)b * H_ + h) * S_ * S_;
    const int s0 = threadIdx.x;
    const int s1 = threadIdx.x + 256;
    float a0 = 0.0f, a1 = 0.0f;
#pragma unroll
    for (int m = 0; m < M_; ++m) {
        if (sv[m]) {
            a0 += arow[(size_t)sp[m] * S_ + s0];
            a1 += arow[(size_t)sp[m] * S_ + s1];
        }
    }
    float* dst = ent_att + ((size_t)be * H_ + h) * S_;
    dst[s0] = a0 * inv_cnt;
    dst[s1] = a1 * inv_cnt;
}

// ---------------------------------------------------------------------------
// K1b: ent_emb[b,e,d] = logsumexp over valid mentions of seq rows
// grid = B*NE blocks, 256 threads
// ---------------------------------------------------------------------------
__global__ void k_ent_emb(const float* __restrict__ seq, const int* __restrict__ mpos,
                          const int* __restrict__ mmask, float* __restrict__ ent_emb) {
    const int be = blockIdx.x;
    const int b  = be / NE_;

    __shared__ int sp[M_];
    __shared__ int sv[M_];
    if (threadIdx.x < M_) {
        int p  = mpos[be * M_ + threadIdx.x] + OFFSET_;
        int v  = (mmask[be * M_ + threadIdx.x] > 0) && (p < S_);
        int pc = p < 0 ? 0 : (p > S_ - 1 ? S_ - 1 : p);
        sp[threadIdx.x] = pc;
        sv[threadIdx.x] = v;
    }
    __syncthreads();

    int cnt = 0;
#pragma unroll
    for (int m = 0; m < M_; ++m) cnt += sv[m];
    const bool has = cnt > 0;

    for (int d = threadIdx.x; d < D_; d += blockDim.x) {
        float vals[M_];
        float mx = -FLT_MAX;
#pragma unroll
        for (int m = 0; m < M_; ++m) {
            float v = sv[m] ? seq[((size_t)b * S_ + sp[m]) * D_ + d] : -FLT_MAX;
            vals[m] = v;
            mx = fmaxf(mx, v);
        }
        float o = 0.0f;
        if (has) {
            float ss = 0.0f;
#pragma unroll
            for (int m = 0; m < M_; ++m)
                if (sv[m]) ss += expf(vals[m] - mx);
            o = mx + logf(ss);
        }
        ent_emb[(size_t)be * D_ + d] = o;
    }
}

// ---------------------------------------------------------------------------
// K2: ht[b,r,s] (bf16) for UNIQUE pairs r -> (i<=j) only (symmetry: ht[i,j]=ht[j,i]).
// Measured-good per-pair-block structure, float2 loads + bf16x2 stores.
// grid = dim3(MU_, B_), 256 threads (thread t owns s=2t, 2t+1)
// ---------------------------------------------------------------------------
__global__ void k_ht(const float* __restrict__ ent_att, __hip_bfloat16* __restrict__ htb) {
    const int r = blockIdx.x;
    const int b = blockIdx.y;
    const int t = threadIdx.x;
    __hip_bfloat16* dst = htb + ((size_t)b * MU_ + r) * S_;

    if (r >= NU_) {             // zero the padding rows
        __hip_bfloat162 z;
        z.x = __float2bfloat16(0.0f);
        z.y = __float2bfloat16(0.0f);
        *reinterpret_cast<__hip_bfloat162*>(&dst[2 * t]) = z;
        return;
    }
    int i, j;
    tri_inv(r, i, j);

    const float* Ai = ent_att + ((size_t)b * NE_ + i) * HS_;
    const float* Aj = ent_att + ((size_t)b * NE_ + j) * HS_;

    float v0 = 0.0f, v1 = 0.0f;
#pragma unroll
    for (int h = 0; h < H_; ++h) {
        const float2 a = *reinterpret_cast<const float2*>(&Ai[h * S_ + 2 * t]);
        const float2 c = *reinterpret_cast<const float2*>(&Aj[h * S_ + 2 * t]);
        v0 = fmaf(a.x, c.x, v0);
        v1 = fmaf(a.y, c.y, v1);
    }
    v0 *= (1.0f / H_);
    v1 *= (1.0f / H_);

    float local = v0 + v1;
#pragma unroll
    for (int off = 32; off > 0; off >>= 1) local += __shfl_xor(local, off, 64);
    __shared__ float wsum[4];
    if ((t & 63) == 0) wsum[t >> 6] = local;
    __syncthreads();
    const float inv = 1.0f / (wsum[0] + wsum[1] + wsum[2] + wsum[3] + 1e-5f);

    __hip_bfloat162 rr;
    rr.x = __float2bfloat16(v0 * inv);
    rr.y = __float2bfloat16(v1 * inv);
    *reinterpret_cast<__hip_bfloat162*>(&dst[2 * t]) = rr;
}

// ---------------------------------------------------------------------------
// K3: rs = ht @ seq via bf16 MFMA over UNIQUE pair rows; epilogue mirror-writes
// each value to (i,j) and (j,i) output rows.
// A = htb (MU_ x 512) bf16, B^T = seqT (768 x 512) bf16, C fp32 -> out[...,1536:].
// 128x64 tile, BK=32, double-buffered LDS prefetch. 256 threads = 4 waves.
// grid = (D/64=12, MU_/128=8, B) = 384 blocks
// ---------------------------------------------------------------------------
__global__ void __launch_bounds__(256)
k_gemm(const __hip_bfloat16* __restrict__ htb, const __hip_bfloat16* __restrict__ seqT,
       float* __restrict__ out) {
    const int b     = blockIdx.z;
    const int tileN = blockIdx.x * 64;
    const int tileM = blockIdx.y * 128;
    const int tid   = threadIdx.x;
    const int w     = tid >> 6;
    const int lane  = tid & 63;
    const int wr    = w >> 1;          // wave row (0..1) -> 64 rows each
    const int wc    = w & 1;           // wave col (0..1) -> 32 cols each

    __shared__ unsigned short As[2][128 * 32];   // [buf][row][k] 8KB each
    __shared__ unsigned short Bs[2][64 * 32];    // [buf][col][k] 4KB each

    const __hip_bfloat16* A  = htb  + (size_t)b * MU_ * S_;
    const __hip_bfloat16* Bt = seqT + (size_t)b * D_ * S_;

    // staging geometry: chunk = 16 rows x 32 cols = 1KB per wave-load
    const int crow = lane >> 2;          // row within chunk (0..15)
    const int ccol = (lane & 3) * 8;     // k within chunk (0,8,16,24)

    // fragment geometry
    const int lr = lane & 15;
    const int lk = (lane >> 4) * 8;

    f32x4 acc[4][2];
#pragma unroll
    for (int mf = 0; mf < 4; ++mf)
#pragma unroll
        for (int nf = 0; nf < 2; ++nf) acc[mf][nf] = (f32x4){0.f, 0.f, 0.f, 0.f};

    // prologue: stage k-tile 0 into buffer 0
    {
#pragma unroll
        for (int q = 0; q < 2; ++q) {
            const int c = w * 2 + q;     // A chunks 0..7
            GLOAD_LDS16(A + (size_t)(tileM + c * 16 + crow) * S_ + ccol, &As[0][c * 512]);
        }
        GLOAD_LDS16(Bt + (size_t)(tileN + w * 16 + crow) * S_ + ccol, &Bs[0][w * 512]);
    }
    __syncthreads();

    for (int it = 0; it < 16; ++it) {
        const int cur = it & 1;
        // prefetch next k-tile into the other buffer (overlaps with MFMA below)
        if (it < 15) {
            const int k0 = (it + 1) * 32;
#pragma unroll
            for (int q = 0; q < 2; ++q) {
                const int c = w * 2 + q;
                GLOAD_LDS16(A + (size_t)(tileM + c * 16 + crow) * S_ + k0 + ccol,
                            &As[cur ^ 1][c * 512]);
            }
            GLOAD_LDS16(Bt + (size_t)(tileN + w * 16 + crow) * S_ + k0 + ccol,
                        &Bs[cur ^ 1][w * 512]);
        }

        short8 af[4], bfr[2];
#pragma unroll
        for (int mf = 0; mf < 4; ++mf)
            af[mf] = *(const short8*)&As[cur][(wr * 64 + mf * 16 + lr) * 32 + lk];
#pragma unroll
        for (int nf = 0; nf < 2; ++nf)
            bfr[nf] = *(const short8*)&Bs[cur][(wc * 32 + nf * 16 + lr) * 32 + lk];
#pragma unroll
        for (int mf = 0; mf < 4; ++mf)
#pragma unroll
            for (int nf = 0; nf < 2; ++nf)
                acc[mf][nf] = __builtin_amdgcn_mfma_f32_16x16x32_bf16(af[mf], bfr[nf], acc[mf][nf], 0, 0, 0);

        __syncthreads();   // drains this iteration's prefetch (vmcnt) + readers
    }

    // epilogue: C/D layout col=lane&15, row=(lane>>4)*4+j; mirror-write (i,j),(j,i)
#pragma unroll
    for (int mf = 0; mf < 4; ++mf) {
        const int row0 = tileM + wr * 64 + mf * 16 + (lane >> 4) * 4;
#pragma unroll
        for (int nf = 0; nf < 2; ++nf) {
            const int col = tileN + wc * 32 + nf * 16 + (lane & 15);
#pragma unroll
            for (int jj = 0; jj < 4; ++jj) {
                const int r = row0 + jj;
                if (r < NU_) {
                    int pi, pj;
                    tri_inv(r, pi, pj);
                    const float v = acc[mf][nf][jj];
                    out[((size_t)(b * NE2_ + pi * NE_ + pj)) * OUTC_ + 2 * D_ + col] = v;
                    if (pi != pj)
                        out[((size_t)(b * NE2_ + pj * NE_ + pi)) * OUTC_ + 2 * D_ + col] = v;
                }
            }
        }
    }
}

// ---------------------------------------------------------------------------
// K4: hs/ts broadcast writes
// ---------------------------------------------------------------------------
__global__ void k_hsts(const float* __restrict__ ent_emb, float* __restrict__ out) {
    const int bij = blockIdx.x;
    const int b   = bij / NE2_;
    const int ij  = bij - b * NE2_;
    const int i   = ij / NE_;
    const int j   = ij - i * NE_;

    const float4* ei = reinterpret_cast<const float4*>(ent_emb + ((size_t)b * NE_ + i) * D_);
    const float4* ej = reinterpret_cast<const float4*>(ent_emb + ((size_t)b * NE_ + j) * D_);
    float4* o = reinterpret_cast<float4*>(out + (size_t)bij * OUTC_);

    for (int t = threadIdx.x; t < D_ / 4; t += blockDim.x) o[t] = ei[t];
    for (int t = threadIdx.x; t < D_ / 4; t += blockDim.x) o[D_ / 4 + t] = ej[t];
}

// ---------------------------------------------------------------------------
extern "C" void kernel_launch(void* const* d_in, const int* in_sizes, int n_in,
                              void* d_out, int out_size, void* d_ws, size_t ws_size,
                              hipStream_t stream) {
    const float* seq   = (const float*)d_in[0];
    const float* att   = (const float*)d_in[1];
    const int*   mpos  = (const int*)d_in[2];
    const int*   mmask = (const int*)d_in[3];
    float* out = (float*)d_out;

    // workspace layout
    float* ent_emb = (float*)d_ws;                               // B*NE*D   fp32
    float* ent_att = ent_emb + (size_t)B_ * NE_ * D_;            // B*NE*H*S fp32
    __hip_bfloat16* htb  = (__hip_bfloat16*)(ent_att + (size_t)B_ * NE_ * HS_); // B*MU*S bf16
    __hip_bfloat16* seqT = htb + (size_t)B_ * MU_ * S_;          // B*D*S bf16

    k_prep<<<dim3(D_ / 64, S_ / 64, B_), 256, 0, stream>>>(seq, seqT);
    k_ent_att<<<B_ * NE_ * H_, 256, 0, stream>>>(att, mpos, mmask, ent_att);
    k_ent_emb<<<B_ * NE_, 256, 0, stream>>>(seq, mpos, mmask, ent_emb);
    k_ht<<<dim3(MU_, B_), 256, 0, stream>>>(ent_att, htb);
    k_gemm<<<dim3(D_ / 64, MU_ / 128, B_), 256, 0, stream>>>(htb, seqT, out);
    k_hsts<<<B_ * NE2_, 256, 0, stream>>>(ent_emb, out);
}

// Round 16
// 141.141 us; speedup vs baseline: 1.3531x; 1.0727x over previous
//
#include <hip/hip_runtime.h>
#include <hip/hip_bf16.h>
#include <cfloat>
#include <cmath>

#define B_ 4
#define S_ 512
#define D_ 768
#define H_ 12
#define NE_ 42
#define M_ 8
#define OFFSET_ 1
#define NE2_ (NE_*NE_)
#define OUTC_ (3*D_)   // 2304
#define HS_ (H_*S_)    // 6144
#define NU_ 903        // NE*(NE+1)/2 unique (i<=j) pairs
#define MU_ 1024       // padded unique-pair rows for the MFMA GEMM (8 * 128)

// fused-grid partition points
#define F1_ATT_ (B_*NE_*H_)          // 2016 ent_att blocks
#define F1_PREP_ (F1_ATT_ + 384)     // +384 prep blocks = 2400
#define F1_TOT_ (F1_PREP_ + B_*NE_)  // +168 emb blocks = 2568
#define F3_GEMM_ 384                 // gemm blocks
#define F3_TOT_ (F3_GEMM_ + B_*NE2_) // +7056 hsts = 7440

typedef __attribute__((ext_vector_type(8))) short short8;
typedef __attribute__((ext_vector_type(4))) float f32x4;

#define GLOAD_LDS16(g, l) __builtin_amdgcn_global_load_lds( \
    (const __attribute__((address_space(1))) unsigned int*)(g), \
    (__attribute__((address_space(3))) unsigned int*)(l), 16, 0, 0)

// triangle-pair index inversion: r = base(i) + (j - i), base(i) = i*(85-i)/2
__device__ __forceinline__ int tri_base(int i) { return (i * (2 * NE_ + 1 - i)) >> 1; }
__device__ __forceinline__ void tri_inv(int r, int& i, int& j) {
    i = (int)floorf(((float)(2 * NE_ + 1)
                     - sqrtf((float)((2 * NE_ + 1) * (2 * NE_ + 1)) - 8.0f * (float)r)) * 0.5f);
    if (i < 0) i = 0;
    while (tri_base(i + 1) <= r) ++i;
    while (tri_base(i) > r) --i;
    j = i + (r - tri_base(i));
}

// ---------------------------------------------------------------------------
// F1: fused {ent_att | prep | ent_emb} — all independent, one dispatch.
//   [0, 2016)      : ent_att[b,e,h,s] = masked mean of gathered attention rows
//   [2016, 2400)   : seqT[b][d][s] = bf16(seq[b][s][d]) 64x64 tile transpose
//   [2400, 2568)   : ent_emb[b,e,d] = logsumexp over valid mentions
// ---------------------------------------------------------------------------
__global__ void __launch_bounds__(256)
k_fused_pre(const float* __restrict__ seq, const float* __restrict__ att,
            const int* __restrict__ mpos, const int* __restrict__ mmask,
            __hip_bfloat16* __restrict__ seqT, float* __restrict__ ent_att,
            float* __restrict__ ent_emb) {
    const int bid = blockIdx.x;
    const int t   = threadIdx.x;

    __shared__ float tile[64][65];   // prep branch only
    __shared__ int sp[M_];
    __shared__ int sv[M_];

    if (bid < F1_ATT_) {
        // ---------------- ent_att ----------------
        const int beh = bid;
        const int h   = beh % H_;
        const int be  = beh / H_;
        const int b   = be / NE_;

        if (t < M_) {
            int p  = mpos[be * M_ + t] + OFFSET_;
            int v  = (mmask[be * M_ + t] > 0) && (p < S_);
            int pc = p < 0 ? 0 : (p > S_ - 1 ? S_ - 1 : p);
            sp[t] = pc;
            sv[t] = v;
        }
        __syncthreads();

        int cnt = 0;
#pragma unroll
        for (int m = 0; m < M_; ++m) cnt += sv[m];
        const float inv_cnt = 1.0f / (float)(cnt > 0 ? cnt : 1);

        const float* arow = att + ((size_t)b * H_ + h) * S_ * S_;
        const int s0 = t;
        const int s1 = t + 256;
        float a0 = 0.0f, a1 = 0.0f;
#pragma unroll
        for (int m = 0; m < M_; ++m) {
            if (sv[m]) {
                a0 += arow[(size_t)sp[m] * S_ + s0];
                a1 += arow[(size_t)sp[m] * S_ + s1];
            }
        }
        float* dst = ent_att + ((size_t)be * H_ + h) * S_;
        dst[s0] = a0 * inv_cnt;
        dst[s1] = a1 * inv_cnt;
    } else if (bid < F1_PREP_) {
        // ---------------- prep (transpose) ----------------
        const int q  = bid - F1_ATT_;
        const int d0 = (q % 12) * 64;
        const int s0 = ((q / 12) % 8) * 64;
        const int b  = q / 96;

#pragma unroll
        for (int i = 0; i < 16; ++i) {
            const int r = (t >> 6) * 16 + i;   // s within tile
            const int c = t & 63;              // d within tile
            tile[r][c] = seq[((size_t)b * S_ + s0 + r) * D_ + d0 + c];
        }
        __syncthreads();
#pragma unroll
        for (int i = 0; i < 16; ++i) {
            const int r = (t >> 6) * 16 + i;   // d within tile
            const int c = t & 63;              // s within tile
            seqT[((size_t)b * D_ + d0 + r) * S_ + s0 + c] = __float2bfloat16(tile[c][r]);
        }
    } else {
        // ---------------- ent_emb (logsumexp) ----------------
        const int be = bid - F1_PREP_;
        const int b  = be / NE_;

        if (t < M_) {
            int p  = mpos[be * M_ + t] + OFFSET_;
            int v  = (mmask[be * M_ + t] > 0) && (p < S_);
            int pc = p < 0 ? 0 : (p > S_ - 1 ? S_ - 1 : p);
            sp[t] = pc;
            sv[t] = v;
        }
        __syncthreads();

        int cnt = 0;
#pragma unroll
        for (int m = 0; m < M_; ++m) cnt += sv[m];
        const bool has = cnt > 0;

        for (int d = t; d < D_; d += 256) {
            float vals[M_];
            float mx = -FLT_MAX;
#pragma unroll
            for (int m = 0; m < M_; ++m) {
                float v = sv[m] ? seq[((size_t)b * S_ + sp[m]) * D_ + d] : -FLT_MAX;
                vals[m] = v;
                mx = fmaxf(mx, v);
            }
            float o = 0.0f;
            if (has) {
                float ss = 0.0f;
#pragma unroll
                for (int m = 0; m < M_; ++m)
                    if (sv[m]) ss += expf(vals[m] - mx);
                o = mx + logf(ss);
            }
            ent_emb[(size_t)be * D_ + d] = o;
        }
    }
}

// ---------------------------------------------------------------------------
// F2: ht[b,r,s] (bf16) for UNIQUE pairs r -> (i<=j). float2 loads, bf16x2 stores.
// grid = dim3(MU_, B_), 256 threads (thread t owns s=2t, 2t+1)
// ---------------------------------------------------------------------------
__global__ void k_ht(const float* __restrict__ ent_att, __hip_bfloat16* __restrict__ htb) {
    const int r = blockIdx.x;
    const int b = blockIdx.y;
    const int t = threadIdx.x;
    __hip_bfloat16* dst = htb + ((size_t)b * MU_ + r) * S_;

    if (r >= NU_) {             // zero the padding rows
        __hip_bfloat162 z;
        z.x = __float2bfloat16(0.0f);
        z.y = __float2bfloat16(0.0f);
        *reinterpret_cast<__hip_bfloat162*>(&dst[2 * t]) = z;
        return;
    }
    int i, j;
    tri_inv(r, i, j);

    const float* Ai = ent_att + ((size_t)b * NE_ + i) * HS_;
    const float* Aj = ent_att + ((size_t)b * NE_ + j) * HS_;

    float v0 = 0.0f, v1 = 0.0f;
#pragma unroll
    for (int h = 0; h < H_; ++h) {
        const float2 a = *reinterpret_cast<const float2*>(&Ai[h * S_ + 2 * t]);
        const float2 c = *reinterpret_cast<const float2*>(&Aj[h * S_ + 2 * t]);
        v0 = fmaf(a.x, c.x, v0);
        v1 = fmaf(a.y, c.y, v1);
    }
    v0 *= (1.0f / H_);
    v1 *= (1.0f / H_);

    float local = v0 + v1;
#pragma unroll
    for (int off = 32; off > 0; off >>= 1) local += __shfl_xor(local, off, 64);
    __shared__ float wsum[4];
    if ((t & 63) == 0) wsum[t >> 6] = local;
    __syncthreads();
    const float inv = 1.0f / (wsum[0] + wsum[1] + wsum[2] + wsum[3] + 1e-5f);

    __hip_bfloat162 rr;
    rr.x = __float2bfloat16(v0 * inv);
    rr.y = __float2bfloat16(v1 * inv);
    *reinterpret_cast<__hip_bfloat162*>(&dst[2 * t]) = rr;
}

// ---------------------------------------------------------------------------
// F3: fused {gemm | hsts} — independent outputs, one dispatch.
//   [0, 384)     : rs = ht @ seq (bf16 MFMA, unique rows, mirror-write epilogue)
//   [384, 7440)  : hs/ts broadcast writes
// ---------------------------------------------------------------------------
__global__ void __launch_bounds__(256)
k_fused_out(const __hip_bfloat16* __restrict__ htb, const __hip_bfloat16* __restrict__ seqT,
            const float* __restrict__ ent_emb, float* __restrict__ out) {
    const int bid = blockIdx.x;
    const int tid = threadIdx.x;

    __shared__ unsigned short As[2][128 * 32];   // gemm branch only (16 KB)
    __shared__ unsigned short Bs[2][64 * 32];    // (8 KB)

    if (bid < F3_GEMM_) {
        // ---------------- gemm ----------------
        const int tileN = (bid % 12) * 64;
        const int tileM = ((bid / 12) % 8) * 128;
        const int b     = bid / 96;
        const int w     = tid >> 6;
        const int lane  = tid & 63;
        const int wr    = w >> 1;
        const int wc    = w & 1;

        const __hip_bfloat16* A  = htb  + (size_t)b * MU_ * S_;
        const __hip_bfloat16* Bt = seqT + (size_t)b * D_ * S_;

        const int crow = lane >> 2;
        const int ccol = (lane & 3) * 8;
        const int lr = lane & 15;
        const int lk = (lane >> 4) * 8;

        f32x4 acc[4][2];
#pragma unroll
        for (int mf = 0; mf < 4; ++mf)
#pragma unroll
            for (int nf = 0; nf < 2; ++nf) acc[mf][nf] = (f32x4){0.f, 0.f, 0.f, 0.f};

        // prologue: stage k-tile 0 into buffer 0
        {
#pragma unroll
            for (int q = 0; q < 2; ++q) {
                const int c = w * 2 + q;
                GLOAD_LDS16(A + (size_t)(tileM + c * 16 + crow) * S_ + ccol, &As[0][c * 512]);
            }
            GLOAD_LDS16(Bt + (size_t)(tileN + w * 16 + crow) * S_ + ccol, &Bs[0][w * 512]);
        }
        __syncthreads();

        for (int it = 0; it < 16; ++it) {
            const int cur = it & 1;
            if (it < 15) {
                const int k0 = (it + 1) * 32;
#pragma unroll
                for (int q = 0; q < 2; ++q) {
                    const int c = w * 2 + q;
                    GLOAD_LDS16(A + (size_t)(tileM + c * 16 + crow) * S_ + k0 + ccol,
                                &As[cur ^ 1][c * 512]);
                }
                GLOAD_LDS16(Bt + (size_t)(tileN + w * 16 + crow) * S_ + k0 + ccol,
                            &Bs[cur ^ 1][w * 512]);
            }

            short8 af[4], bfr[2];
#pragma unroll
            for (int mf = 0; mf < 4; ++mf)
                af[mf] = *(const short8*)&As[cur][(wr * 64 + mf * 16 + lr) * 32 + lk];
#pragma unroll
            for (int nf = 0; nf < 2; ++nf)
                bfr[nf] = *(const short8*)&Bs[cur][(wc * 32 + nf * 16 + lr) * 32 + lk];
#pragma unroll
            for (int mf = 0; mf < 4; ++mf)
#pragma unroll
                for (int nf = 0; nf < 2; ++nf)
                    acc[mf][nf] = __builtin_amdgcn_mfma_f32_16x16x32_bf16(af[mf], bfr[nf], acc[mf][nf], 0, 0, 0);

            __syncthreads();
        }

        // epilogue: mirror-write (i,j),(j,i)
#pragma unroll
        for (int mf = 0; mf < 4; ++mf) {
            const int row0 = tileM + wr * 64 + mf * 16 + (lane >> 4) * 4;
#pragma unroll
            for (int nf = 0; nf < 2; ++nf) {
                const int col = tileN + wc * 32 + nf * 16 + (lane & 15);
#pragma unroll
                for (int jj = 0; jj < 4; ++jj) {
                    const int r = row0 + jj;
                    if (r < NU_) {
                        int pi, pj;
                        tri_inv(r, pi, pj);
                        const float v = acc[mf][nf][jj];
                        out[((size_t)(b * NE2_ + pi * NE_ + pj)) * OUTC_ + 2 * D_ + col] = v;
                        if (pi != pj)
                            out[((size_t)(b * NE2_ + pj * NE_ + pi)) * OUTC_ + 2 * D_ + col] = v;
                    }
                }
            }
        }
    } else {
        // ---------------- hsts ----------------
        const int bij = bid - F3_GEMM_;
        const int b   = bij / NE2_;
        const int ij  = bij - b * NE2_;
        const int i   = ij / NE_;
        const int j   = ij - i * NE_;

        const float4* ei = reinterpret_cast<const float4*>(ent_emb + ((size_t)b * NE_ + i) * D_);
        const float4* ej = reinterpret_cast<const float4*>(ent_emb + ((size_t)b * NE_ + j) * D_);
        float4* o = reinterpret_cast<float4*>(out + (size_t)bij * OUTC_);

        for (int t = tid; t < D_ / 4; t += 256) o[t] = ei[t];
        for (int t = tid; t < D_ / 4; t += 256) o[D_ / 4 + t] = ej[t];
    }
}

// ---------------------------------------------------------------------------
extern "C" void kernel_launch(void* const* d_in, const int* in_sizes, int n_in,
                              void* d_out, int out_size, void* d_ws, size_t ws_size,
                              hipStream_t stream) {
    const float* seq   = (const float*)d_in[0];
    const float* att   = (const float*)d_in[1];
    const int*   mpos  = (const int*)d_in[2];
    const int*   mmask = (const int*)d_in[3];
    float* out = (float*)d_out;

    // workspace layout
    float* ent_emb = (float*)d_ws;                               // B*NE*D   fp32
    float* ent_att = ent_emb + (size_t)B_ * NE_ * D_;            // B*NE*H*S fp32
    __hip_bfloat16* htb  = (__hip_bfloat16*)(ent_att + (size_t)B_ * NE_ * HS_); // B*MU*S bf16
    __hip_bfloat16* seqT = htb + (size_t)B_ * MU_ * S_;          // B*D*S bf16

    k_fused_pre<<<F1_TOT_, 256, 0, stream>>>(seq, att, mpos, mmask, seqT, ent_att, ent_emb);
    k_ht<<<dim3(MU_, B_), 256, 0, stream>>>(ent_att, htb);
    k_fused_out<<<F3_TOT_, 256, 0, stream>>>(htb, seqT, ent_emb, out);
}